// Round 3
// baseline (801.890 us; speedup 1.0000x reference)
//
#include <hip/hip_runtime.h>
#include <hip/hip_bf16.h>
#include <math.h>

// ---------- types ----------
typedef __bf16 bf16x8 __attribute__((ext_vector_type(8)));
typedef float  f32x4  __attribute__((ext_vector_type(4)));

struct __align__(8) bf16x4s { __hip_bfloat16 a, b, c, d; };

__device__ __forceinline__ void gload_lds16(const void* g, void* l) {
  __builtin_amdgcn_global_load_lds(
      (const __attribute__((address_space(1))) void*)g,
      (__attribute__((address_space(3))) void*)l, 16, 0, 0);
}

__device__ __forceinline__ float fast_gelu(float v) {
  // gelu(v) = 0.5 v (1 + erf(v/sqrt2)), erf via A&S 7.1.26 (|err|<=1.5e-7), branchless
  float s = 0.70710678118654752f * v;
  float a = fabsf(s);
  float t = __builtin_amdgcn_rcpf(fmaf(0.3275911f, a, 1.0f));
  float p = t * fmaf(t, fmaf(t, fmaf(t, fmaf(t, 1.061405429f, -1.453152027f),
                                     1.421413741f), -0.284496736f), 0.254829592f);
  float e = __expf(-a * a);
  float er = copysignf(fmaf(-p, e, 1.0f), s);
  return 0.5f * v * (1.0f + er);
}

// ---------- GEMM: C[M,N] = A[M,K](bf16,row) * B[N,K]^T(bf16,row) ----------
// 2-phase double-buffered pipeline (T3 minimum recipe) + XCD-chunked block swizzle (T1).
// grid: x = M-blocks, y = N-blocks, z = K-split (EPI2 writes to per-z slab).
// EPI 0: u1' = bf16( W[b,p] * gelu(acc + b1[p,e]) )   (p=n>>10, b=m>>5)
// EPI 2: f32out[slab + m*N + n] = acc
template<int BM, int BN, int EPI>
__global__ __launch_bounds__(256)
void gemm_nt(const __hip_bfloat16* __restrict__ A,
             const __hip_bfloat16* __restrict__ B,
             const int K, const int Kc, const int N,
             const float* __restrict__ p0,   // EPI0: b1[P,1024]
             const float* __restrict__ p1,   // EPI0: W[B,P]
             float* __restrict__ f32out,     // EPI2: out/partials
             __hip_bfloat16* __restrict__ bfout) // EPI0: u1
{
  __shared__ __align__(16) __hip_bfloat16 sA[2 * BM * 64];
  __shared__ __align__(16) __hip_bfloat16 sB[2 * BN * 64];
  constexpr int WR = BM / 2, WC = BN / 2;
  constexpr int MI = WR / 16, NJ = WC / 16;
  constexpr int CPA = BM / 32, CPB = BN / 32;  // 1KB staging chunks per wave

  const int tid = threadIdx.x;
  const int lane = tid & 63, wid = tid >> 6;
  const int l15 = lane & 15, l4 = lane >> 4;
  const int r8 = lane >> 3, blk = lane & 7;

  // XCD-aware chunked swizzle: consecutive tiles -> same XCD L2 (nwg % 8 == 0 for all grids)
  const int nx = gridDim.x;
  const int flat = blockIdx.x + nx * blockIdx.y;
  const int q = (nx * gridDim.y) >> 3;
  const int nid = (flat & 7) * q + (flat >> 3);
  const long m0 = (long)(nid % nx) * BM;
  const long n0 = (long)(nid / nx) * BN;

  const int kbeg = blockIdx.z * Kc;
  const int wr = (wid >> 1) * WR, wc = (wid & 1) * WC;

  f32x4 acc[MI][NJ] = {};

  // stage tile [rows][64] with 16B-block XOR swizzle applied on the GLOBAL side
  auto stage = [&](int buf, int k0) {
    __hip_bfloat16* dA = sA + buf * (BM * 64);
    __hip_bfloat16* dB = sB + buf * (BN * 64);
#pragma unroll
    for (int c = 0; c < CPA; ++c) {
      int ch = wid * CPA + c;
      int row = ch * 8 + r8;
      gload_lds16(A + (m0 + row) * (long)K + k0 + ((blk ^ r8) << 3), dA + ch * 512);
    }
#pragma unroll
    for (int c = 0; c < CPB; ++c) {
      int ch = wid * CPB + c;
      int row = ch * 8 + r8;
      gload_lds16(B + (n0 + row) * (long)K + k0 + ((blk ^ r8) << 3), dB + ch * 512);
    }
  };

  const int nt = Kc / 64;
  stage(0, kbeg);
  __syncthreads();
  int cur = 0;
  for (int t = 0; t < nt; ++t) {
    if (t + 1 < nt) stage(cur ^ 1, kbeg + (t + 1) * 64);  // prefetch in flight under compute
    const __hip_bfloat16* pA = sA + cur * (BM * 64);
    const __hip_bfloat16* pB = sB + cur * (BN * 64);
#pragma unroll
    for (int kk = 0; kk < 2; ++kk) {
      bf16x8 af[MI], bfr[NJ];
#pragma unroll
      for (int mi = 0; mi < MI; ++mi) {
        int row = wr + mi * 16 + l15;
        af[mi] = *(const bf16x8*)(pA + row * 64 + (((kk * 4 + l4) ^ (row & 7)) << 3));
      }
#pragma unroll
      for (int nj = 0; nj < NJ; ++nj) {
        int row = wc + nj * 16 + l15;
        bfr[nj] = *(const bf16x8*)(pB + row * 64 + (((kk * 4 + l4) ^ (row & 7)) << 3));
      }
#pragma unroll
      for (int mi = 0; mi < MI; ++mi)
#pragma unroll
        for (int nj = 0; nj < NJ; ++nj)
          acc[mi][nj] = __builtin_amdgcn_mfma_f32_16x16x32_bf16(af[mi], bfr[nj], acc[mi][nj], 0, 0, 0);
    }
    __syncthreads();  // drains vmcnt(0)+lgkmcnt(0): next buffer staged, this one consumed
    cur ^= 1;
  }

  // epilogue: D[row=(l>>4)*4+r][col=l&15] per 16x16 frag (m89-verified layout)
  const long slab = (EPI == 2) ? (long)blockIdx.z * (long)(gridDim.x * BM) * N : 0;
#pragma unroll
  for (int mi = 0; mi < MI; ++mi) {
    const long gmb = m0 + wr + mi * 16 + l4 * 4;   // rows gmb..gmb+3 (same batch b)
    const int b = (int)(gmb >> 5);
#pragma unroll
    for (int nj = 0; nj < NJ; ++nj) {
      const long gn = n0 + wc + nj * 16 + l15;
      if constexpr (EPI == 0) {
        const int p = (int)(gn >> 10), e = (int)(gn & 1023);
        const float bias = p0[(p << 10) + e];
        const float wpb = p1[(b << 3) + p];
#pragma unroll
        for (int r = 0; r < 4; ++r) {
          float v = fast_gelu(acc[mi][nj][r] + bias) * wpb;
          bfout[(gmb + r) * (long)N + gn] = __float2bfloat16(v);
        }
      } else {
#pragma unroll
        for (int r = 0; r < 4; ++r)
          f32out[slab + (gmb + r) * (long)N + gn] = acc[mi][nj][r];
      }
    }
  }
}

// ---------- small kernels ----------
__global__ void cvt_bf16_k(const float* __restrict__ in, __hip_bfloat16* __restrict__ out, long n) {
  long i = ((long)blockIdx.x * blockDim.x + threadIdx.x) * 4;
  if (i >= n) return;
  float4 v = *(const float4*)(in + i);
  *(bf16x4s*)(out + i) = bf16x4s{__float2bfloat16(v.x), __float2bfloat16(v.y),
                                 __float2bfloat16(v.z), __float2bfloat16(v.w)};
}

// out[c*out_rs + p*out_bs + r] = bf16(in[p*in_bs + r*1024 + c]), tiles of 32x32
__global__ void tconv_k(const float* __restrict__ in, __hip_bfloat16* __restrict__ out,
                        long in_bs, long out_rs, long out_bs) {
  __shared__ float tile[32][33];
  int p = blockIdx.z;
  int r0 = blockIdx.y * 32, c0 = blockIdx.x * 32;
  int tx = threadIdx.x, ty = threadIdx.y;
#pragma unroll
  for (int i = 0; i < 32; i += 8)
    tile[ty + i][tx] = in[(long)p * in_bs + (long)(r0 + ty + i) * 1024 + c0 + tx];
  __syncthreads();
#pragma unroll
  for (int i = 0; i < 32; i += 8)
    out[(long)(c0 + ty + i) * out_rs + (long)p * out_bs + (r0 + tx)] =
        __float2bfloat16(tile[tx][ty + i]);
}

__global__ void embed_k(const int* __restrict__ x, const float* __restrict__ emb,
                        const float* __restrict__ pos, float* __restrict__ h,
                        __hip_bfloat16* __restrict__ hb, float* __restrict__ divp) {
  int row = blockIdx.x;          // b*32 + t
  int t = row & 31;
  int c = threadIdx.x * 4;
  long tok = x[row];
  float4 e = *(const float4*)(emb + tok * 1024 + c);
  float4 q = *(const float4*)(pos + (long)t * 1024 + c);
  float4 v{e.x + q.x, e.y + q.y, e.z + q.z, e.w + q.w};
  *(float4*)(h + (long)row * 1024 + c) = v;
  *(bf16x4s*)(hb + (long)row * 1024 + c) =
      bf16x4s{__float2bfloat16(v.x), __float2bfloat16(v.y),
              __float2bfloat16(v.z), __float2bfloat16(v.w)};
  if (row == 0 && threadIdx.x == 0) *divp = 0.f;
}

__global__ void select_k(const float* __restrict__ h, const float* __restrict__ selw,
                         const float* __restrict__ selb, const float* __restrict__ gum,
                         float* __restrict__ W, int dep) {
  int b = blockIdx.x, tid = threadIdx.x;
  int c = tid * 4;
  float4 s{0.f, 0.f, 0.f, 0.f};
  for (int t = 0; t < 32; ++t) {
    const float4 v = *(const float4*)(h + ((long)(b * 32 + t)) * 1024 + c);
    s.x += v.x; s.y += v.y; s.z += v.z; s.w += v.w;
  }
  float lp[8];
#pragma unroll
  for (int p = 0; p < 8; ++p) {
    const float4 w = *(const float4*)(selw + dep * 8192 + p * 1024 + c);
    lp[p] = (s.x * w.x + s.y * w.y + s.z * w.z + s.w * w.w) * (1.f / 32.f);
  }
  int lane = tid & 63, wid = tid >> 6;
#pragma unroll
  for (int p = 0; p < 8; ++p)
    for (int o = 32; o; o >>= 1) lp[p] += __shfl_down(lp[p], o);
  __shared__ float red[4][8];
  if (lane == 0) {
#pragma unroll
    for (int p = 0; p < 8; ++p) red[wid][p] = lp[p];
  }
  __syncthreads();
  if (tid == 0) {
    float lg[8], mx = -1e30f;
    for (int p = 0; p < 8; ++p) {
      lg[p] = red[0][p] + red[1][p] + red[2][p] + red[3][p]
            + selb[dep * 8 + p] + gum[dep * 512 + b * 8 + p];
      mx = fmaxf(mx, lg[p]);
    }
    float sm = 0.f;
    for (int p = 0; p < 8; ++p) { lg[p] = expf(lg[p] - mx); sm += lg[p]; }
    float inv = 1.f / sm;
    for (int p = 0; p < 8; ++p) W[b * 8 + p] = lg[p] * inv;
  }
}

// wb2[b,:] = sum_p W[b,p]*b2[p,:]; block 0 thread 0 also accumulates KL div term
__global__ void wb2_k(const float* __restrict__ W, const float* __restrict__ b2,
                      float* __restrict__ wb2, float* __restrict__ divp) {
  int b = blockIdx.x;
  int c = threadIdx.x * 4;
  float4 a{0.f, 0.f, 0.f, 0.f};
#pragma unroll
  for (int p = 0; p < 8; ++p) {
    float wp = W[b * 8 + p];
    const float4 v = *(const float4*)(b2 + p * 1024 + c);
    a.x += wp * v.x; a.y += wp * v.y; a.z += wp * v.z; a.w += wp * v.w;
  }
  *(float4*)(wb2 + (long)b * 1024 + c) = a;
  if (b == 0 && threadIdx.x == 0) {
    float s[8] = {0.f, 0.f, 0.f, 0.f, 0.f, 0.f, 0.f, 0.f};
    for (int bb = 0; bb < 64; ++bb)
#pragma unroll
      for (int p = 0; p < 8; ++p) s[p] += W[bb * 8 + p];
    float d = *divp;
    const float u = 0.125f, lu = logf(0.125f);
#pragma unroll
    for (int p = 0; p < 8; ++p) d += u * (lu - logf(s[p] * (1.f / 64.f)));
    *divp = d;
  }
}

// h += wb2 + sum_s part[s]; write h f32 + bf16
__global__ void h_update_k(const float* __restrict__ part, float* __restrict__ h,
                           const float* __restrict__ wb2, __hip_bfloat16* __restrict__ hb) {
  int row = blockIdx.x;
  int c = threadIdx.x * 4;
  long idx = (long)row * 1024 + c;
  float4 a = *(const float4*)(h + idx);
  const float4 w = *(const float4*)(wb2 + (long)(row >> 5) * 1024 + c);
  a.x += w.x; a.y += w.y; a.z += w.z; a.w += w.w;
#pragma unroll
  for (int s = 0; s < 4; ++s) {
    const float4 v = *(const float4*)(part + (long)s * 2097152 + idx);
    a.x += v.x; a.y += v.y; a.z += v.z; a.w += v.w;
  }
  *(float4*)(h + idx) = a;
  *(bf16x4s*)(hb + idx) = bf16x4s{__float2bfloat16(a.x), __float2bfloat16(a.y),
                                  __float2bfloat16(a.z), __float2bfloat16(a.w)};
}

__global__ void ln_k(const float* __restrict__ h, const float* __restrict__ g,
                     const float* __restrict__ be, __hip_bfloat16* __restrict__ hnb,
                     const float* __restrict__ divp, float* __restrict__ divout) {
  int row = blockIdx.x, tid = threadIdx.x;
  int c = tid * 4;
  const float4 v = *(const float4*)(h + (long)row * 1024 + c);
  float s = v.x + v.y + v.z + v.w;
  float q = v.x * v.x + v.y * v.y + v.z * v.z + v.w * v.w;
  for (int o = 32; o; o >>= 1) { s += __shfl_down(s, o); q += __shfl_down(q, o); }
  __shared__ float red[16];
  int lane = tid & 63, wid = tid >> 6;
  if (lane == 0) { red[wid] = s; red[8 + wid] = q; }
  __syncthreads();
  if (tid == 0) {
    float S = red[0] + red[1] + red[2] + red[3];
    float Q = red[8] + red[9] + red[10] + red[11];
    float mu = S * (1.f / 1024.f);
    float var = Q * (1.f / 1024.f) - mu * mu;
    red[0] = mu; red[1] = rsqrtf(var + 1e-5f);
  }
  __syncthreads();
  float mu = red[0], rs = red[1];
  float4 gg = *(const float4*)(g + c), bb = *(const float4*)(be + c);
  *(bf16x4s*)(hnb + (long)row * 1024 + c) =
      bf16x4s{__float2bfloat16((v.x - mu) * rs * gg.x + bb.x),
              __float2bfloat16((v.y - mu) * rs * gg.y + bb.y),
              __float2bfloat16((v.z - mu) * rs * gg.z + bb.z),
              __float2bfloat16((v.w - mu) * rs * gg.w + bb.w)};
  if (row == 0 && tid == 0) *divout = *divp;
}

// ---------- launch ----------
extern "C" void kernel_launch(void* const* d_in, const int* in_sizes, int n_in,
                              void* d_out, int out_size, void* d_ws, size_t ws_size,
                              hipStream_t stream) {
  (void)in_sizes; (void)n_in; (void)out_size; (void)ws_size;
  const int*   x     = (const int*)  d_in[0];
  const float* emb   = (const float*)d_in[1];
  const float* pos   = (const float*)d_in[2];
  const float* w1    = (const float*)d_in[3];
  const float* b1    = (const float*)d_in[4];
  const float* w2    = (const float*)d_in[5];
  const float* b2    = (const float*)d_in[6];
  const float* selw  = (const float*)d_in[7];
  const float* selb  = (const float*)d_in[8];
  const float* lng   = (const float*)d_in[9];
  const float* lnb   = (const float*)d_in[10];
  const float* headw = (const float*)d_in[11];
  const float* gum   = (const float*)d_in[12];
  float* out = (float*)d_out;

  char* ws = (char*)d_ws;
  __hip_bfloat16* w1t   = (__hip_bfloat16*)(ws);               // [8192,1024] bf16  16 MiB
  __hip_bfloat16* w2t   = (__hip_bfloat16*)(ws + 16777216);    // [1024,8192] bf16  16 MiB
  __hip_bfloat16* headb = (__hip_bfloat16*)(ws + 33554432);    // [32000,1024] bf16 62.5 MiB
  float*          h     = (float*)(ws + 99090432);             // [2048,1024] f32   8 MiB
  __hip_bfloat16* hb    = (__hip_bfloat16*)(ws + 107479040);   // [2048,1024] bf16  4 MiB
  __hip_bfloat16* u1    = (__hip_bfloat16*)(ws + 111673344);   // [2048,8192] bf16  32 MiB
  float*          W     = (float*)(ws + 145227776);            // [64,8]
  float*          wb2   = (float*)(ws + 145229824);            // [64,1024]
  float*          divp  = (float*)(ws + 145491968);            // scalar
  float*          part  = out;  // GEMM2 split-K partials: 4 x [2048,1024] f32 = 32 MiB,
                                // scratch inside d_out (256 MiB), overwritten by head GEMM later

  cvt_bf16_k<<<32000, 256, 0, stream>>>(headw, headb, 32768000L);
  tconv_k<<<dim3(32, 32, 8), dim3(32, 8), 0, stream>>>(w1, w1t, 1L << 20, 1024L, 1L << 20);
  tconv_k<<<dim3(32, 32, 8), dim3(32, 8), 0, stream>>>(w2, w2t, 1L << 20, 8192L, 1024L);
  embed_k<<<2048, 256, 0, stream>>>(x, emb, pos, h, hb, divp);

  for (int d = 0; d < 4; ++d) {
    select_k<<<64, 256, 0, stream>>>(h, selw, selb, gum, W, d);
    wb2_k<<<64, 256, 0, stream>>>(W, b2, wb2, divp);
    // u1' = W * gelu(h @ w1 + b1)   : M=2048 N=8192 K=1024
    gemm_nt<128, 128, 0><<<dim3(16, 64), 256, 0, stream>>>(hb, w1t, 1024, 1024, 8192, b1, W, nullptr, u1);
    // partials[z] = u1' @ w2 (K chunk z) : M=2048 N=1024 K=8192, split-K x4
    gemm_nt<64, 128, 2><<<dim3(32, 8, 4), 256, 0, stream>>>(u1, w2t, 8192, 2048, 1024, nullptr, nullptr, part, nullptr);
    h_update_k<<<2048, 256, 0, stream>>>(part, h, wb2, hb);
  }

  ln_k<<<2048, 256, 0, stream>>>(h, lng, lnb, hb, divp, out + 65536000L);
  // logits = hn @ head_w^T          : M=2048 N=32000 K=1024
  gemm_nt<128, 128, 2><<<dim3(16, 250), 256, 0, stream>>>(hb, headb, 1024, 1024, 32000, nullptr, nullptr, out, nullptr);
}

// Round 4
// 670.366 us; speedup vs baseline: 1.1962x; 1.1962x over previous
//
#include <hip/hip_runtime.h>
#include <hip/hip_bf16.h>
#include <math.h>

// ---------- types ----------
typedef __bf16 bf16x8 __attribute__((ext_vector_type(8)));
typedef float  f32x4  __attribute__((ext_vector_type(4)));

struct __align__(8) bf16x4s { __hip_bfloat16 a, b, c, d; };

__device__ __forceinline__ void gload_lds16(const void* g, void* l) {
  __builtin_amdgcn_global_load_lds(
      (const __attribute__((address_space(1))) void*)g,
      (__attribute__((address_space(3))) void*)l, 16, 0, 0);
}

__device__ __forceinline__ float fast_gelu(float v) {
  // gelu(v) = 0.5 v (1 + erf(v/sqrt2)), erf via A&S 7.1.26 (|err|<=1.5e-7), branchless
  float s = 0.70710678118654752f * v;
  float a = fabsf(s);
  float t = __builtin_amdgcn_rcpf(fmaf(0.3275911f, a, 1.0f));
  float p = t * fmaf(t, fmaf(t, fmaf(t, fmaf(t, 1.061405429f, -1.453152027f),
                                     1.421413741f), -0.284496736f), 0.254829592f);
  float e = __expf(-a * a);
  float er = copysignf(fmaf(-p, e, 1.0f), s);
  return 0.5f * v * (1.0f + er);
}

// ---------- GEMM: C[M,N] = A[M,K](bf16,row) * B[N,K]^T(bf16,row) ----------
// 256x256 tile, BK=64, 512 thr = 8 waves (2M x 4N), per-wave out 128x64.
// 2-K-tile-deep pipeline, counted vmcnt(8) (never 0 in loop), raw barriers,
// setprio around MFMA clusters, T2 swizzle (pre-swizzled global src + swizzled ds_read).
// grid: x = M-blocks, y = N-blocks (XCD-chunk swizzled), z = K-split (EPI2 per-z slab).
// EPI 0: u1' = bf16( W[b,p] * gelu(acc + b1[p,e]) )   (p=n>>10, b=m>>5)
// EPI 2: f32out[slab + m*N + n] = acc
template<int EPI>
__global__ __launch_bounds__(512, 2)
void gemm_nt(const __hip_bfloat16* __restrict__ A,
             const __hip_bfloat16* __restrict__ B,
             const int K, const int Kc, const int N,
             const float* __restrict__ p0,   // EPI0: b1[P,1024]
             const float* __restrict__ p1,   // EPI0: W[B,P]
             float* __restrict__ f32out,     // EPI2: out/partials
             __hip_bfloat16* __restrict__ bfout) // EPI0: u1
{
  // lds layout: A bufs at [buf*16384], B bufs at [32768 + buf*16384]; 128 KiB total
  __shared__ __align__(16) __hip_bfloat16 lds[65536];

  const int tid = threadIdx.x;
  const int lane = tid & 63, wid = tid >> 6;
  const int l15 = lane & 15, l4 = lane >> 4;
  const int r8 = lane >> 3, blk = lane & 7;
  const int wm = wid >> 2, wn = wid & 3;   // 2 x 4 wave grid

  // XCD-aware chunked swizzle (nwg % 8 == 0 for all grids used here)
  const int nx = gridDim.x;
  const int flat = blockIdx.x + nx * blockIdx.y;
  const int q = (nx * gridDim.y) >> 3;
  const int nid = (flat & 7) * q + (flat >> 3);
  const long m0 = (long)(nid % nx) * 256;
  const long n0 = (long)(nid / nx) * 256;

  const int kbeg = blockIdx.z * Kc;
  const int nt = Kc / 64;

  f32x4 acc[8][4] = {};

  // stage one K-tile (A 256x64 + B 256x64) into buf; 8 gload_lds16 per thread.
  // dest linear per wave-chunk; global source pre-XOR-swizzled (rule 21).
  auto stage = [&](int buf, int k0) {
    __hip_bfloat16* dA = lds + buf * 16384;
    __hip_bfloat16* dB = lds + 32768 + buf * 16384;
#pragma unroll
    for (int p2 = 0; p2 < 4; ++p2) {
      int ch = p2 * 8 + wid;            // 0..31
      int row = ch * 8 + r8;            // 0..255
      gload_lds16(A + (m0 + row) * (long)K + k0 + ((blk ^ r8) << 3), dA + ch * 512);
    }
#pragma unroll
    for (int p2 = 0; p2 < 4; ++p2) {
      int ch = p2 * 8 + wid;
      int row = ch * 8 + r8;
      gload_lds16(B + (n0 + row) * (long)K + k0 + ((blk ^ r8) << 3), dB + ch * 512);
    }
  };

  // prologue: kt0 -> buf0, kt1 -> buf1; gate kt0 landed (8 loads of kt1 in flight)
  stage(0, kbeg);
  stage(1, kbeg + 64);
  asm volatile("s_waitcnt vmcnt(8)" ::: "memory");
  __builtin_amdgcn_sched_barrier(0);
  __builtin_amdgcn_s_barrier();

  for (int t = 0; t < nt; ++t) {
    const __hip_bfloat16* pA = lds + (t & 1) * 16384;
    const __hip_bfloat16* pB = lds + 32768 + (t & 1) * 16384;

    // ---- phase 0: read A-quad0 + all B, MFMA quad0 ----
    bf16x8 a0[4][2], bv[4][2];
#pragma unroll
    for (int mi = 0; mi < 4; ++mi)
#pragma unroll
      for (int kk = 0; kk < 2; ++kk) {
        int row = wm * 128 + mi * 16 + l15;
        a0[mi][kk] = *(const bf16x8*)(pA + row * 64 + (((kk * 4 + l4) ^ (row & 7)) << 3));
      }
#pragma unroll
    for (int nj = 0; nj < 4; ++nj)
#pragma unroll
      for (int kk = 0; kk < 2; ++kk) {
        int row = wn * 64 + nj * 16 + l15;
        bv[nj][kk] = *(const bf16x8*)(pB + row * 64 + (((kk * 4 + l4) ^ (row & 7)) << 3));
      }
    __builtin_amdgcn_s_setprio(1);
#pragma unroll
    for (int mi = 0; mi < 4; ++mi)
#pragma unroll
      for (int nj = 0; nj < 4; ++nj)
#pragma unroll
        for (int kk = 0; kk < 2; ++kk)
          acc[mi][nj] = __builtin_amdgcn_mfma_f32_16x16x32_bf16(a0[mi][kk], bv[nj][kk], acc[mi][nj], 0, 0, 0);
    __builtin_amdgcn_s_setprio(0);

    // ---- phase 1 reads: A-quad1 ----
    bf16x8 a1[4][2];
#pragma unroll
    for (int mi = 0; mi < 4; ++mi)
#pragma unroll
      for (int kk = 0; kk < 2; ++kk) {
        int row = wm * 128 + 64 + mi * 16 + l15;
        a1[mi][kk] = *(const bf16x8*)(pA + row * 64 + (((kk * 4 + l4) ^ (row & 7)) << 3));
      }
    // all reads of buf (t&1) drained before barrier -> safe to re-stage it
    asm volatile("s_waitcnt lgkmcnt(0)" ::: "memory");
    __builtin_amdgcn_sched_barrier(0);
    __builtin_amdgcn_s_barrier();

    // ---- stage kt+2 into the just-freed buffer; counted vmcnt gates kt+1 ----
    if (t + 2 < nt) {
      stage(t & 1, kbeg + (t + 2) * 64);
      asm volatile("s_waitcnt vmcnt(8)" ::: "memory");  // kt+1 landed; kt+2 in flight
    } else {
      asm volatile("s_waitcnt vmcnt(0)" ::: "memory");  // tail only
    }
    __builtin_amdgcn_sched_barrier(0);
    __builtin_amdgcn_s_barrier();

    // ---- phase 1 MFMA (registers only; overlaps other waves' staging) ----
    __builtin_amdgcn_s_setprio(1);
#pragma unroll
    for (int mi = 0; mi < 4; ++mi)
#pragma unroll
      for (int nj = 0; nj < 4; ++nj)
#pragma unroll
        for (int kk = 0; kk < 2; ++kk)
          acc[4 + mi][nj] = __builtin_amdgcn_mfma_f32_16x16x32_bf16(a1[mi][kk], bv[nj][kk], acc[4 + mi][nj], 0, 0, 0);
    __builtin_amdgcn_s_setprio(0);
  }

  // epilogue: D[row=(l>>4)*4+r][col=l&15] per 16x16 frag (m89-verified layout)
  const long slab = (EPI == 2) ? (long)blockIdx.z * (long)(gridDim.x * 256) * N : 0;
#pragma unroll
  for (int mi = 0; mi < 8; ++mi) {
    const long gmb = m0 + wm * 128 + mi * 16 + l4 * 4;   // rows gmb..gmb+3 (same batch b)
    const int b = (int)(gmb >> 5);
#pragma unroll
    for (int nj = 0; nj < 4; ++nj) {
      const long gn = n0 + wn * 64 + nj * 16 + l15;
      if constexpr (EPI == 0) {
        const int p = (int)(gn >> 10), e = (int)(gn & 1023);
        const float bias = p0[(p << 10) + e];
        const float wpb = p1[(b << 3) + p];
#pragma unroll
        for (int r = 0; r < 4; ++r) {
          float v = fast_gelu(acc[mi][nj][r] + bias) * wpb;
          bfout[(gmb + r) * (long)N + gn] = __float2bfloat16(v);
        }
      } else {
#pragma unroll
        for (int r = 0; r < 4; ++r)
          f32out[slab + (gmb + r) * (long)N + gn] = acc[mi][nj][r];
      }
    }
  }
}

// ---------- small kernels ----------
__global__ void cvt_bf16_k(const float* __restrict__ in, __hip_bfloat16* __restrict__ out, long n) {
  long i = ((long)blockIdx.x * blockDim.x + threadIdx.x) * 4;
  if (i >= n) return;
  float4 v = *(const float4*)(in + i);
  *(bf16x4s*)(out + i) = bf16x4s{__float2bfloat16(v.x), __float2bfloat16(v.y),
                                 __float2bfloat16(v.z), __float2bfloat16(v.w)};
}

// out[c*out_rs + p*out_bs + r] = bf16(in[p*in_bs + r*1024 + c]), tiles of 32x32
__global__ void tconv_k(const float* __restrict__ in, __hip_bfloat16* __restrict__ out,
                        long in_bs, long out_rs, long out_bs) {
  __shared__ float tile[32][33];
  int p = blockIdx.z;
  int r0 = blockIdx.y * 32, c0 = blockIdx.x * 32;
  int tx = threadIdx.x, ty = threadIdx.y;
#pragma unroll
  for (int i = 0; i < 32; i += 8)
    tile[ty + i][tx] = in[(long)p * in_bs + (long)(r0 + ty + i) * 1024 + c0 + tx];
  __syncthreads();
#pragma unroll
  for (int i = 0; i < 32; i += 8)
    out[(long)(c0 + ty + i) * out_rs + (long)p * out_bs + (r0 + tx)] =
        __float2bfloat16(tile[tx][ty + i]);
}

__global__ void embed_k(const int* __restrict__ x, const float* __restrict__ emb,
                        const float* __restrict__ pos, float* __restrict__ h,
                        __hip_bfloat16* __restrict__ hb, float* __restrict__ divp) {
  int row = blockIdx.x;          // b*32 + t
  int t = row & 31;
  int c = threadIdx.x * 4;
  long tok = x[row];
  float4 e = *(const float4*)(emb + tok * 1024 + c);
  float4 q = *(const float4*)(pos + (long)t * 1024 + c);
  float4 v{e.x + q.x, e.y + q.y, e.z + q.z, e.w + q.w};
  *(float4*)(h + (long)row * 1024 + c) = v;
  *(bf16x4s*)(hb + (long)row * 1024 + c) =
      bf16x4s{__float2bfloat16(v.x), __float2bfloat16(v.y),
              __float2bfloat16(v.z), __float2bfloat16(v.w)};
  if (row == 0 && threadIdx.x == 0) *divp = 0.f;
}

__global__ void select_k(const float* __restrict__ h, const float* __restrict__ selw,
                         const float* __restrict__ selb, const float* __restrict__ gum,
                         float* __restrict__ W, int dep) {
  int b = blockIdx.x, tid = threadIdx.x;
  int c = tid * 4;
  float4 s{0.f, 0.f, 0.f, 0.f};
  for (int t = 0; t < 32; ++t) {
    const float4 v = *(const float4*)(h + ((long)(b * 32 + t)) * 1024 + c);
    s.x += v.x; s.y += v.y; s.z += v.z; s.w += v.w;
  }
  float lp[8];
#pragma unroll
  for (int p = 0; p < 8; ++p) {
    const float4 w = *(const float4*)(selw + dep * 8192 + p * 1024 + c);
    lp[p] = (s.x * w.x + s.y * w.y + s.z * w.z + s.w * w.w) * (1.f / 32.f);
  }
  int lane = tid & 63, wid = tid >> 6;
#pragma unroll
  for (int p = 0; p < 8; ++p)
    for (int o = 32; o; o >>= 1) lp[p] += __shfl_down(lp[p], o);
  __shared__ float red[4][8];
  if (lane == 0) {
#pragma unroll
    for (int p = 0; p < 8; ++p) red[wid][p] = lp[p];
  }
  __syncthreads();
  if (tid == 0) {
    float lg[8], mx = -1e30f;
    for (int p = 0; p < 8; ++p) {
      lg[p] = red[0][p] + red[1][p] + red[2][p] + red[3][p]
            + selb[dep * 8 + p] + gum[dep * 512 + b * 8 + p];
      mx = fmaxf(mx, lg[p]);
    }
    float sm = 0.f;
    for (int p = 0; p < 8; ++p) { lg[p] = expf(lg[p] - mx); sm += lg[p]; }
    float inv = 1.f / sm;
    for (int p = 0; p < 8; ++p) W[b * 8 + p] = lg[p] * inv;
  }
}

// wb2[b,:] = sum_p W[b,p]*b2[p,:]; block 0 thread 0 also accumulates KL div term
__global__ void wb2_k(const float* __restrict__ W, const float* __restrict__ b2,
                      float* __restrict__ wb2, float* __restrict__ divp) {
  int b = blockIdx.x;
  int c = threadIdx.x * 4;
  float4 a{0.f, 0.f, 0.f, 0.f};
#pragma unroll
  for (int p = 0; p < 8; ++p) {
    float wp = W[b * 8 + p];
    const float4 v = *(const float4*)(b2 + p * 1024 + c);
    a.x += wp * v.x; a.y += wp * v.y; a.z += wp * v.z; a.w += wp * v.w;
  }
  *(float4*)(wb2 + (long)b * 1024 + c) = a;
  if (b == 0 && threadIdx.x == 0) {
    float s[8] = {0.f, 0.f, 0.f, 0.f, 0.f, 0.f, 0.f, 0.f};
    for (int bb = 0; bb < 64; ++bb)
#pragma unroll
      for (int p = 0; p < 8; ++p) s[p] += W[bb * 8 + p];
    float d = *divp;
    const float u = 0.125f, lu = logf(0.125f);
#pragma unroll
    for (int p = 0; p < 8; ++p) d += u * (lu - logf(s[p] * (1.f / 64.f)));
    *divp = d;
  }
}

// h += wb2 + sum_s part[s] (8 split-K slabs); write h f32 + bf16
__global__ void h_update_k(const float* __restrict__ part, float* __restrict__ h,
                           const float* __restrict__ wb2, __hip_bfloat16* __restrict__ hb) {
  int row = blockIdx.x;
  int c = threadIdx.x * 4;
  long idx = (long)row * 1024 + c;
  float4 a = *(const float4*)(h + idx);
  const float4 w = *(const float4*)(wb2 + (long)(row >> 5) * 1024 + c);
  a.x += w.x; a.y += w.y; a.z += w.z; a.w += w.w;
#pragma unroll
  for (int s = 0; s < 8; ++s) {
    const float4 v = *(const float4*)(part + (long)s * 2097152 + idx);
    a.x += v.x; a.y += v.y; a.z += v.z; a.w += v.w;
  }
  *(float4*)(h + idx) = a;
  *(bf16x4s*)(hb + idx) = bf16x4s{__float2bfloat16(a.x), __float2bfloat16(a.y),
                                  __float2bfloat16(a.z), __float2bfloat16(a.w)};
}

__global__ void ln_k(const float* __restrict__ h, const float* __restrict__ g,
                     const float* __restrict__ be, __hip_bfloat16* __restrict__ hnb,
                     const float* __restrict__ divp, float* __restrict__ divout) {
  int row = blockIdx.x, tid = threadIdx.x;
  int c = tid * 4;
  const float4 v = *(const float4*)(h + (long)row * 1024 + c);
  float s = v.x + v.y + v.z + v.w;
  float q = v.x * v.x + v.y * v.y + v.z * v.z + v.w * v.w;
  for (int o = 32; o; o >>= 1) { s += __shfl_down(s, o); q += __shfl_down(q, o); }
  __shared__ float red[16];
  int lane = tid & 63, wid = tid >> 6;
  if (lane == 0) { red[wid] = s; red[8 + wid] = q; }
  __syncthreads();
  if (tid == 0) {
    float S = red[0] + red[1] + red[2] + red[3];
    float Q = red[8] + red[9] + red[10] + red[11];
    float mu = S * (1.f / 1024.f);
    float var = Q * (1.f / 1024.f) - mu * mu;
    red[0] = mu; red[1] = rsqrtf(var + 1e-5f);
  }
  __syncthreads();
  float mu = red[0], rs = red[1];
  float4 gg = *(const float4*)(g + c), bb = *(const float4*)(be + c);
  *(bf16x4s*)(hnb + (long)row * 1024 + c) =
      bf16x4s{__float2bfloat16((v.x - mu) * rs * gg.x + bb.x),
              __float2bfloat16((v.y - mu) * rs * gg.y + bb.y),
              __float2bfloat16((v.z - mu) * rs * gg.z + bb.z),
              __float2bfloat16((v.w - mu) * rs * gg.w + bb.w)};
  if (row == 0 && tid == 0) *divout = *divp;
}

// ---------- launch ----------
extern "C" void kernel_launch(void* const* d_in, const int* in_sizes, int n_in,
                              void* d_out, int out_size, void* d_ws, size_t ws_size,
                              hipStream_t stream) {
  (void)in_sizes; (void)n_in; (void)out_size; (void)ws_size;
  const int*   x     = (const int*)  d_in[0];
  const float* emb   = (const float*)d_in[1];
  const float* pos   = (const float*)d_in[2];
  const float* w1    = (const float*)d_in[3];
  const float* b1    = (const float*)d_in[4];
  const float* w2    = (const float*)d_in[5];
  const float* b2    = (const float*)d_in[6];
  const float* selw  = (const float*)d_in[7];
  const float* selb  = (const float*)d_in[8];
  const float* lng   = (const float*)d_in[9];
  const float* lnb   = (const float*)d_in[10];
  const float* headw = (const float*)d_in[11];
  const float* gum   = (const float*)d_in[12];
  float* out = (float*)d_out;

  char* ws = (char*)d_ws;
  __hip_bfloat16* w1t   = (__hip_bfloat16*)(ws);               // [8192,1024] bf16  16 MiB
  __hip_bfloat16* w2t   = (__hip_bfloat16*)(ws + 16777216);    // [1024,8192] bf16  16 MiB
  __hip_bfloat16* headb = (__hip_bfloat16*)(ws + 33554432);    // [32000,1024] bf16 62.5 MiB
  float*          h     = (float*)(ws + 99090432);             // [2048,1024] f32   8 MiB
  __hip_bfloat16* hb    = (__hip_bfloat16*)(ws + 107479040);   // [2048,1024] bf16  4 MiB
  __hip_bfloat16* u1    = (__hip_bfloat16*)(ws + 111673344);   // [2048,8192] bf16  32 MiB
  float*          W     = (float*)(ws + 145227776);            // [64,8]
  float*          wb2   = (float*)(ws + 145229824);            // [64,1024]
  float*          divp  = (float*)(ws + 145491968);            // scalar
  float*          part  = out;  // GEMM2 split-K partials: 8 x [2048,1024] f32 = 64 MiB,
                                // scratch inside d_out (262 MiB), overwritten by head GEMM later

  cvt_bf16_k<<<32000, 256, 0, stream>>>(headw, headb, 32768000L);
  tconv_k<<<dim3(32, 32, 8), dim3(32, 8), 0, stream>>>(w1, w1t, 1L << 20, 1024L, 1L << 20);
  tconv_k<<<dim3(32, 32, 8), dim3(32, 8), 0, stream>>>(w2, w2t, 1L << 20, 8192L, 1024L);
  embed_k<<<2048, 256, 0, stream>>>(x, emb, pos, h, hb, divp);

  for (int d = 0; d < 4; ++d) {
    select_k<<<64, 256, 0, stream>>>(h, selw, selb, gum, W, d);
    wb2_k<<<64, 256, 0, stream>>>(W, b2, wb2, divp);
    // u1' = W * gelu(h @ w1 + b1)   : M=2048 N=8192 K=1024  (8x32 = 256 blocks, 1/CU)
    gemm_nt<0><<<dim3(8, 32), 512, 0, stream>>>(hb, w1t, 1024, 1024, 8192, b1, W, nullptr, u1);
    // partials[z] = u1' @ w2 (K chunk z) : M=2048 N=1024 K=8192, split-K x8 (256 blocks)
    gemm_nt<2><<<dim3(8, 4, 8), 512, 0, stream>>>(u1, w2t, 8192, 1024, 1024, nullptr, nullptr, part, nullptr);
    h_update_k<<<2048, 256, 0, stream>>>(part, h, wb2, hb);
  }

  ln_k<<<2048, 256, 0, stream>>>(h, lng, lnb, hb, divp, out + 65536000L);
  // logits = hn @ head_w^T          : M=2048 N=32000 K=1024  (8x125 = 1000 blocks)
  gemm_nt<2><<<dim3(8, 125), 512, 0, stream>>>(hb, headb, 1024, 1024, 32000, nullptr, nullptr, out, nullptr);
}

// Round 5
// 655.774 us; speedup vs baseline: 1.2228x; 1.0223x over previous
//
#include <hip/hip_runtime.h>
#include <hip/hip_bf16.h>
#include <math.h>

// ---------- types ----------
typedef __bf16 bf16x8 __attribute__((ext_vector_type(8)));
typedef float  f32x4  __attribute__((ext_vector_type(4)));

struct __align__(8) bf16x4s { __hip_bfloat16 a, b, c, d; };

__device__ __forceinline__ void gload_lds16(const void* g, void* l) {
  __builtin_amdgcn_global_load_lds(
      (const __attribute__((address_space(1))) void*)g,
      (__attribute__((address_space(3))) void*)l, 16, 0, 0);
}

__device__ __forceinline__ float fast_gelu(float v) {
  // gelu(v) = 0.5 v (1 + erf(v/sqrt2)), erf via A&S 7.1.26 (|err|<=1.5e-7), branchless
  float s = 0.70710678118654752f * v;
  float a = fabsf(s);
  float t = __builtin_amdgcn_rcpf(fmaf(0.3275911f, a, 1.0f));
  float p = t * fmaf(t, fmaf(t, fmaf(t, fmaf(t, 1.061405429f, -1.453152027f),
                                     1.421413741f), -0.284496736f), 0.254829592f);
  float e = __expf(-a * a);
  float er = copysignf(fmaf(-p, e, 1.0f), s);
  return 0.5f * v * (1.0f + er);
}

#define BAR()   asm volatile("s_barrier" ::: "memory")
#define LGKM0() do { asm volatile("s_waitcnt lgkmcnt(0)" ::: "memory"); \
                     __builtin_amdgcn_sched_barrier(0); } while (0)
#define VMC(N)  do { asm volatile("s_waitcnt vmcnt(" #N ")" ::: "memory"); \
                     __builtin_amdgcn_sched_barrier(0); } while (0)
#define P1()    __builtin_amdgcn_s_setprio(1)
#define P0()    __builtin_amdgcn_s_setprio(0)

// ---------- GEMM: C[M,N] = A[M,K](bf16,row) * B[N,K]^T(bf16,row) ----------
// 256x256 tile, BK=64, 512 thr = 8 waves (2M x 4N), per-wave out 128x64.
// 4-phase-per-K-tile fine interleave (m201-style): each phase =
//   {ds_read subtile ; stage 1 half-tile ; barrier ; lgkmcnt(0) ;
//    setprio(1) MFMA x16 setprio(0) ; counted vmcnt ; barrier}.
// LDS half-buffers defined by consumption phase:
//   A-early (row%128<64, read pi0), A-late (pi2), B-early (row%64<32, pi0), B-late (pi1).
// Stage cycle per tile s: pi0->A-L(s+1), pi1->A-E(s+2), pi2->B-E(s+2), pi3->B-L(s+2).
// Steady gates vmcnt(10) = 5 stages x 2 loads in flight; tail drains 10->8->4->2->0.
// EPI 0: u1' = bf16( W[b,p] * gelu(acc + b1[p,e]) )   (p=n>>10, b=m>>5)
// EPI 2: f32out[slab + m*N + n] = acc
template<int EPI>
__global__ __launch_bounds__(512, 2)
void gemm_nt(const __hip_bfloat16* __restrict__ A,
             const __hip_bfloat16* __restrict__ B,
             const int K, const int Kc, const int N,
             const float* __restrict__ p0,   // EPI0: b1[P,1024]
             const float* __restrict__ p1,   // EPI0: W[B,P]
             float* __restrict__ f32out,     // EPI2: out/partials
             __hip_bfloat16* __restrict__ bfout) // EPI0: u1
{
  // A bufs at elems [buf*16384], B bufs at [32768 + buf*16384]; 128 KiB total
  __shared__ __align__(16) __hip_bfloat16 lds[65536];

  const int tid = threadIdx.x;
  const int lane = tid & 63, wid = tid >> 6;
  const int l15 = lane & 15, l4 = lane >> 4;
  const int r8 = lane >> 3, blk = lane & 7;
  const int wm = wid >> 2, wn = wid & 3;   // 2 x 4 wave grid

  // XCD-aware chunked swizzle (nwg % 8 == 0 for all grids used here)
  const int nx = gridDim.x;
  const int flat = blockIdx.x + nx * blockIdx.y;
  const int q = (nx * gridDim.y) >> 3;
  const int nid = (flat & 7) * q + (flat >> 3);
  const long m0 = (long)(nid % nx) * 256;
  const long n0 = (long)(nid / nx) * 256;

  const int kbeg = blockIdx.z * Kc;
  const int nt = Kc / 64;

  f32x4 acc[8][4] = {};
  bf16x8 ar[4][2], br[4][2];

  // stage one half-tile (128 rows x 64 cols = 16 KB): 2 gload_lds16 per thread.
  // A half h: chunks with (ch%16)>>3 == h ; B half h: chunks with (ch%8)>>2 == h.
  auto stageA = [&](int buf, int h, int k0) {
#pragma unroll
    for (int p2 = 0; p2 < 2; ++p2) {
      int ch = p2 * 16 + h * 8 + wid;
      int row = ch * 8 + r8;
      gload_lds16(A + (m0 + row) * (long)K + k0 + ((blk ^ r8) << 3),
                  lds + buf * 16384 + ch * 512);
    }
  };
  auto stageB = [&](int buf, int h, int k0) {
#pragma unroll
    for (int p2 = 0; p2 < 2; ++p2) {
      int ch = (p2 * 2 + (wid >> 2)) * 8 + h * 4 + (wid & 3);
      int row = ch * 8 + r8;
      gload_lds16(B + (n0 + row) * (long)K + k0 + ((blk ^ r8) << 3),
                  lds + 32768 + buf * 16384 + ch * 512);
    }
  };
  // register loads (XOR-swizzled ds_read_b128)
  auto readA = [&](const __hip_bfloat16* pA, int mih) {
#pragma unroll
    for (int mi = 0; mi < 4; ++mi)
#pragma unroll
      for (int kk = 0; kk < 2; ++kk) {
        int row = wm * 128 + mih * 64 + mi * 16 + l15;
        ar[mi][kk] = *(const bf16x8*)(pA + row * 64 + (((kk * 4 + l4) ^ (row & 7)) << 3));
      }
  };
  auto readB2 = [&](const __hip_bfloat16* pB, int njh) {
#pragma unroll
    for (int nj = 0; nj < 2; ++nj)
#pragma unroll
      for (int kk = 0; kk < 2; ++kk) {
        int row = wn * 64 + njh * 32 + nj * 16 + l15;
        br[njh * 2 + nj][kk] = *(const bf16x8*)(pB + row * 64 + (((kk * 4 + l4) ^ (row & 7)) << 3));
      }
  };
  auto mfma8 = [&](int mib, int njb) {   // 16 MFMA: one C-quadrant over K=64
#pragma unroll
    for (int mi = 0; mi < 4; ++mi)
#pragma unroll
      for (int nj = 0; nj < 2; ++nj)
#pragma unroll
        for (int kk = 0; kk < 2; ++kk)
          acc[mib + mi][njb + nj] = __builtin_amdgcn_mfma_f32_16x16x32_bf16(
              ar[mi][kk], br[njb + nj][kk], acc[mib + mi][njb + nj], 0, 0, 0);
  };

  // ---- prologue: 7 half-stages in steady-state order; gate oldest 2 (A-E0,B-E0) ----
  stageA(0, 0, kbeg);        // A-E(0)
  stageB(0, 0, kbeg);        // B-E(0)
  stageB(0, 1, kbeg);        // B-L(0)
  stageA(0, 1, kbeg);        // A-L(0)
  stageA(1, 0, kbeg + 64);   // A-E(1)
  stageB(1, 0, kbeg + 64);   // B-E(1)
  stageB(1, 1, kbeg + 64);   // B-L(1)
  VMC(10);
  BAR();

  // ---- main loop: tiles 0 .. nt-3, full staging, uniform vmcnt(10) ----
  for (int s = 0; s < nt - 2; ++s) {
    const int b = s & 1;
    const __hip_bfloat16* pA = lds + b * 16384;
    const __hip_bfloat16* pB = lds + 32768 + b * 16384;
    const int k1 = kbeg + (s + 1) * 64, k2 = kbeg + (s + 2) * 64;
    // pi0: read A-E + B-E ; stage A-L(s+1)
    readA(pA, 0); readB2(pB, 0);
    stageA(b ^ 1, 1, k1);
    BAR(); LGKM0();
    P1(); mfma8(0, 0); P0();
    VMC(10); BAR();
    // pi1: read B-L ; stage A-E(s+2)
    readB2(pB, 1);
    stageA(b, 0, k2);
    BAR(); LGKM0();
    P1(); mfma8(0, 2); P0();
    VMC(10); BAR();
    // pi2: read A-L ; stage B-E(s+2)
    readA(pA, 1);
    stageB(b, 0, k2);
    BAR(); LGKM0();
    P1(); mfma8(4, 0); P0();
    BAR();
    // pi3: stage B-L(s+2)
    stageB(b, 1, k2);
    BAR();
    P1(); mfma8(4, 2); P0();
    VMC(10); BAR();
  }

  // ---- tail tile nt-2: only stages A-L(nt-1); gates 10 / 8 / - / 4 ----
  {
    const int b = (nt - 2) & 1;
    const __hip_bfloat16* pA = lds + b * 16384;
    const __hip_bfloat16* pB = lds + 32768 + b * 16384;
    readA(pA, 0); readB2(pB, 0);
    stageA(b ^ 1, 1, kbeg + (nt - 1) * 64);
    BAR(); LGKM0();
    P1(); mfma8(0, 0); P0();
    VMC(10); BAR();
    readB2(pB, 1);
    BAR(); LGKM0();
    P1(); mfma8(0, 2); P0();
    VMC(8); BAR();
    readA(pA, 1);
    BAR(); LGKM0();
    P1(); mfma8(4, 0); P0();
    BAR();
    BAR();
    P1(); mfma8(4, 2); P0();
    VMC(4); BAR();
  }
  // ---- tail tile nt-1: no stages; gates 2 / 0 (fully drained at exit) ----
  {
    const int b = (nt - 1) & 1;
    const __hip_bfloat16* pA = lds + b * 16384;
    const __hip_bfloat16* pB = lds + 32768 + b * 16384;
    readA(pA, 0); readB2(pB, 0);
    BAR(); LGKM0();
    P1(); mfma8(0, 0); P0();
    VMC(2); BAR();
    readB2(pB, 1);
    BAR(); LGKM0();
    P1(); mfma8(0, 2); P0();
    VMC(0); BAR();
    readA(pA, 1);
    BAR(); LGKM0();
    P1(); mfma8(4, 0); P0();
    BAR();
    BAR();
    P1(); mfma8(4, 2); P0();
    BAR();
  }

  // epilogue: D[row=(l>>4)*4+r][col=l&15] per 16x16 frag (m89-verified layout)
  const long slab = (EPI == 2) ? (long)blockIdx.z * (long)(gridDim.x * 256) * N : 0;
#pragma unroll
  for (int mi = 0; mi < 8; ++mi) {
    const long gmb = m0 + wm * 128 + mi * 16 + l4 * 4;   // rows gmb..gmb+3 (same batch b)
    const int b = (int)(gmb >> 5);
#pragma unroll
    for (int nj = 0; nj < 4; ++nj) {
      const long gn = n0 + wn * 64 + nj * 16 + l15;
      if constexpr (EPI == 0) {
        const int p = (int)(gn >> 10), e = (int)(gn & 1023);
        const float bias = p0[(p << 10) + e];
        const float wpb = p1[(b << 3) + p];
#pragma unroll
        for (int r = 0; r < 4; ++r) {
          float v = fast_gelu(acc[mi][nj][r] + bias) * wpb;
          bfout[(gmb + r) * (long)N + gn] = __float2bfloat16(v);
        }
      } else {
#pragma unroll
        for (int r = 0; r < 4; ++r)
          f32out[slab + (gmb + r) * (long)N + gn] = acc[mi][nj][r];
      }
    }
  }
}

// ---------- small kernels ----------
__global__ void cvt_bf16_k(const float* __restrict__ in, __hip_bfloat16* __restrict__ out, long n) {
  long i = ((long)blockIdx.x * blockDim.x + threadIdx.x) * 4;
  if (i >= n) return;
  float4 v = *(const float4*)(in + i);
  *(bf16x4s*)(out + i) = bf16x4s{__float2bfloat16(v.x), __float2bfloat16(v.y),
                                 __float2bfloat16(v.z), __float2bfloat16(v.w)};
}

// out[c*out_rs + p*out_bs + r] = bf16(in[p*in_bs + r*1024 + c]), tiles of 32x32
__global__ void tconv_k(const float* __restrict__ in, __hip_bfloat16* __restrict__ out,
                        long in_bs, long out_rs, long out_bs) {
  __shared__ float tile[32][33];
  int p = blockIdx.z;
  int r0 = blockIdx.y * 32, c0 = blockIdx.x * 32;
  int tx = threadIdx.x, ty = threadIdx.y;
#pragma unroll
  for (int i = 0; i < 32; i += 8)
    tile[ty + i][tx] = in[(long)p * in_bs + (long)(r0 + ty + i) * 1024 + c0 + tx];
  __syncthreads();
#pragma unroll
  for (int i = 0; i < 32; i += 8)
    out[(long)(c0 + ty + i) * out_rs + (long)p * out_bs + (r0 + tx)] =
        __float2bfloat16(tile[tx][ty + i]);
}

__global__ void embed_k(const int* __restrict__ x, const float* __restrict__ emb,
                        const float* __restrict__ pos, float* __restrict__ h,
                        __hip_bfloat16* __restrict__ hb, float* __restrict__ divp) {
  int row = blockIdx.x;          // b*32 + t
  int t = row & 31;
  int c = threadIdx.x * 4;
  long tok = x[row];
  float4 e = *(const float4*)(emb + tok * 1024 + c);
  float4 q = *(const float4*)(pos + (long)t * 1024 + c);
  float4 v{e.x + q.x, e.y + q.y, e.z + q.z, e.w + q.w};
  *(float4*)(h + (long)row * 1024 + c) = v;
  *(bf16x4s*)(hb + (long)row * 1024 + c) =
      bf16x4s{__float2bfloat16(v.x), __float2bfloat16(v.y),
              __float2bfloat16(v.z), __float2bfloat16(v.w)};
  if (row == 0 && threadIdx.x == 0) *divp = 0.f;
}

__global__ void select_k(const float* __restrict__ h, const float* __restrict__ selw,
                         const float* __restrict__ selb, const float* __restrict__ gum,
                         float* __restrict__ W, int dep) {
  int b = blockIdx.x, tid = threadIdx.x;
  int c = tid * 4;
  float4 s{0.f, 0.f, 0.f, 0.f};
  for (int t = 0; t < 32; ++t) {
    const float4 v = *(const float4*)(h + ((long)(b * 32 + t)) * 1024 + c);
    s.x += v.x; s.y += v.y; s.z += v.z; s.w += v.w;
  }
  float lp[8];
#pragma unroll
  for (int p = 0; p < 8; ++p) {
    const float4 w = *(const float4*)(selw + dep * 8192 + p * 1024 + c);
    lp[p] = (s.x * w.x + s.y * w.y + s.z * w.z + s.w * w.w) * (1.f / 32.f);
  }
  int lane = tid & 63, wid = tid >> 6;
#pragma unroll
  for (int p = 0; p < 8; ++p)
    for (int o = 32; o; o >>= 1) lp[p] += __shfl_down(lp[p], o);
  __shared__ float red[4][8];
  if (lane == 0) {
#pragma unroll
    for (int p = 0; p < 8; ++p) red[wid][p] = lp[p];
  }
  __syncthreads();
  if (tid == 0) {
    float lg[8], mx = -1e30f;
    for (int p = 0; p < 8; ++p) {
      lg[p] = red[0][p] + red[1][p] + red[2][p] + red[3][p]
            + selb[dep * 8 + p] + gum[dep * 512 + b * 8 + p];
      mx = fmaxf(mx, lg[p]);
    }
    float sm = 0.f;
    for (int p = 0; p < 8; ++p) { lg[p] = expf(lg[p] - mx); sm += lg[p]; }
    float inv = 1.f / sm;
    for (int p = 0; p < 8; ++p) W[b * 8 + p] = lg[p] * inv;
  }
}

// wb2[b,:] = sum_p W[b,p]*b2[p,:]; block 0 thread 0 also accumulates KL div term
__global__ void wb2_k(const float* __restrict__ W, const float* __restrict__ b2,
                      float* __restrict__ wb2, float* __restrict__ divp) {
  int b = blockIdx.x;
  int c = threadIdx.x * 4;
  float4 a{0.f, 0.f, 0.f, 0.f};
#pragma unroll
  for (int p = 0; p < 8; ++p) {
    float wp = W[b * 8 + p];
    const float4 v = *(const float4*)(b2 + p * 1024 + c);
    a.x += wp * v.x; a.y += wp * v.y; a.z += wp * v.z; a.w += wp * v.w;
  }
  *(float4*)(wb2 + (long)b * 1024 + c) = a;
  if (b == 0 && threadIdx.x == 0) {
    float s[8] = {0.f, 0.f, 0.f, 0.f, 0.f, 0.f, 0.f, 0.f};
    for (int bb = 0; bb < 64; ++bb)
#pragma unroll
      for (int p = 0; p < 8; ++p) s[p] += W[bb * 8 + p];
    float d = *divp;
    const float u = 0.125f, lu = logf(0.125f);
#pragma unroll
    for (int p = 0; p < 8; ++p) d += u * (lu - logf(s[p] * (1.f / 64.f)));
    *divp = d;
  }
}

// h += wb2 + sum_s part[s] (8 split-K slabs); write h f32 + bf16
__global__ void h_update_k(const float* __restrict__ part, float* __restrict__ h,
                           const float* __restrict__ wb2, __hip_bfloat16* __restrict__ hb) {
  int row = blockIdx.x;
  int c = threadIdx.x * 4;
  long idx = (long)row * 1024 + c;
  float4 a = *(const float4*)(h + idx);
  const float4 w = *(const float4*)(wb2 + (long)(row >> 5) * 1024 + c);
  a.x += w.x; a.y += w.y; a.z += w.z; a.w += w.w;
#pragma unroll
  for (int s = 0; s < 8; ++s) {
    const float4 v = *(const float4*)(part + (long)s * 2097152 + idx);
    a.x += v.x; a.y += v.y; a.z += v.z; a.w += v.w;
  }
  *(float4*)(h + idx) = a;
  *(bf16x4s*)(hb + idx) = bf16x4s{__float2bfloat16(a.x), __float2bfloat16(a.y),
                                  __float2bfloat16(a.z), __float2bfloat16(a.w)};
}

__global__ void ln_k(const float* __restrict__ h, const float* __restrict__ g,
                     const float* __restrict__ be, __hip_bfloat16* __restrict__ hnb,
                     const float* __restrict__ divp, float* __restrict__ divout) {
  int row = blockIdx.x, tid = threadIdx.x;
  int c = tid * 4;
  const float4 v = *(const float4*)(h + (long)row * 1024 + c);
  float s = v.x + v.y + v.z + v.w;
  float q = v.x * v.x + v.y * v.y + v.z * v.z + v.w * v.w;
  for (int o = 32; o; o >>= 1) { s += __shfl_down(s, o); q += __shfl_down(q, o); }
  __shared__ float red[16];
  int lane = tid & 63, wid = tid >> 6;
  if (lane == 0) { red[wid] = s; red[8 + wid] = q; }
  __syncthreads();
  if (tid == 0) {
    float S = red[0] + red[1] + red[2] + red[3];
    float Q = red[8] + red[9] + red[10] + red[11];
    float mu = S * (1.f / 1024.f);
    float var = Q * (1.f / 1024.f) - mu * mu;
    red[0] = mu; red[1] = rsqrtf(var + 1e-5f);
  }
  __syncthreads();
  float mu = red[0], rs = red[1];
  float4 gg = *(const float4*)(g + c), bb = *(const float4*)(be + c);
  *(bf16x4s*)(hnb + (long)row * 1024 + c) =
      bf16x4s{__float2bfloat16((v.x - mu) * rs * gg.x + bb.x),
              __float2bfloat16((v.y - mu) * rs * gg.y + bb.y),
              __float2bfloat16((v.z - mu) * rs * gg.z + bb.z),
              __float2bfloat16((v.w - mu) * rs * gg.w + bb.w)};
  if (row == 0 && tid == 0) *divout = *divp;
}

// ---------- launch ----------
extern "C" void kernel_launch(void* const* d_in, const int* in_sizes, int n_in,
                              void* d_out, int out_size, void* d_ws, size_t ws_size,
                              hipStream_t stream) {
  (void)in_sizes; (void)n_in; (void)out_size; (void)ws_size;
  const int*   x     = (const int*)  d_in[0];
  const float* emb   = (const float*)d_in[1];
  const float* pos   = (const float*)d_in[2];
  const float* w1    = (const float*)d_in[3];
  const float* b1    = (const float*)d_in[4];
  const float* w2    = (const float*)d_in[5];
  const float* b2    = (const float*)d_in[6];
  const float* selw  = (const float*)d_in[7];
  const float* selb  = (const float*)d_in[8];
  const float* lng   = (const float*)d_in[9];
  const float* lnb   = (const float*)d_in[10];
  const float* headw = (const float*)d_in[11];
  const float* gum   = (const float*)d_in[12];
  float* out = (float*)d_out;

  char* ws = (char*)d_ws;
  __hip_bfloat16* w1t   = (__hip_bfloat16*)(ws);               // [8192,1024] bf16  16 MiB
  __hip_bfloat16* w2t   = (__hip_bfloat16*)(ws + 16777216);    // [1024,8192] bf16  16 MiB
  __hip_bfloat16* headb = (__hip_bfloat16*)(ws + 33554432);    // [32000,1024] bf16 62.5 MiB
  float*          h     = (float*)(ws + 99090432);             // [2048,1024] f32   8 MiB
  __hip_bfloat16* hb    = (__hip_bfloat16*)(ws + 107479040);   // [2048,1024] bf16  4 MiB
  __hip_bfloat16* u1    = (__hip_bfloat16*)(ws + 111673344);   // [2048,8192] bf16  32 MiB
  float*          W     = (float*)(ws + 145227776);            // [64,8]
  float*          wb2   = (float*)(ws + 145229824);            // [64,1024]
  float*          divp  = (float*)(ws + 145491968);            // scalar
  float*          part  = out;  // GEMM2 split-K partials: 8 x [2048,1024] f32 = 64 MiB,
                                // scratch inside d_out (262 MiB), overwritten by head GEMM later

  cvt_bf16_k<<<32000, 256, 0, stream>>>(headw, headb, 32768000L);
  tconv_k<<<dim3(32, 32, 8), dim3(32, 8), 0, stream>>>(w1, w1t, 1L << 20, 1024L, 1L << 20);
  tconv_k<<<dim3(32, 32, 8), dim3(32, 8), 0, stream>>>(w2, w2t, 1L << 20, 8192L, 1024L);
  embed_k<<<2048, 256, 0, stream>>>(x, emb, pos, h, hb, divp);

  for (int d = 0; d < 4; ++d) {
    select_k<<<64, 256, 0, stream>>>(h, selw, selb, gum, W, d);
    wb2_k<<<64, 256, 0, stream>>>(W, b2, wb2, divp);
    // u1' = W * gelu(h @ w1 + b1)   : M=2048 N=8192 K=1024  (8x32 = 256 blocks, 1/CU)
    gemm_nt<0><<<dim3(8, 32), 512, 0, stream>>>(hb, w1t, 1024, 1024, 8192, b1, W, nullptr, u1);
    // partials[z] = u1' @ w2 (K chunk z) : M=2048 N=1024 K=8192, split-K x8 (256 blocks)
    gemm_nt<2><<<dim3(8, 4, 8), 512, 0, stream>>>(u1, w2t, 8192, 1024, 1024, nullptr, nullptr, part, nullptr);
    h_update_k<<<2048, 256, 0, stream>>>(part, h, wb2, hb);
  }

  ln_k<<<2048, 256, 0, stream>>>(h, lng, lnb, hb, divp, out + 65536000L);
  // logits = hn @ head_w^T          : M=2048 N=32000 K=1024  (8x125 = 1000 blocks)
  gemm_nt<2><<<dim3(8, 125), 512, 0, stream>>>(hb, headb, 1024, 1024, 32000, nullptr, nullptr, out, nullptr);
}